// Round 6
// baseline (50.699 us; speedup 1.0000x reference)
//
#include <hip/hip_runtime.h>
#include <math.h>

#define C      128
#define CAPLG  12
#define CAP    (1 << CAPLG)      // bucket capacity per class (max count ~2300 << 4096)
#define SPLIT  16                // blocks per class in main pass
#define NMB    (C * SPLIT)       // 2048 main blocks
#define SPB    1024              // samples per scatter block
#define CSTR   16                // cursor stride in ints -> one 64B line per class
#define LN2F   0.69314718056f

__device__ __forceinline__ float fast_rcp(float x) { return __builtin_amdgcn_rcpf(x); }

// ---------------------------------------------------------------------------
// Bucketed counting-sort scatter. cursor2 is line-padded (CSTR ints/class) so
// the 32K global atomics spread across 128 cache lines instead of 2.
__global__ __launch_bounds__(256)
void scatter_kernel(const int* __restrict__ tgt, int* __restrict__ cursor2,
                    int* __restrict__ perm, int B) {
    __shared__ int lcur[C];
    __shared__ int sbase[C];
    if (threadIdx.x < C) lcur[threadIdx.x] = 0;
    __syncthreads();
    const int base = blockIdx.x * SPB;
    int myt[SPB / 256], myr[SPB / 256];
#pragma unroll
    for (int j = 0; j < SPB / 256; ++j) {
        int i = base + j * 256 + threadIdx.x;
        if (i < B) { myt[j] = tgt[i]; myr[j] = atomicAdd(&lcur[myt[j]], 1); }
        else myt[j] = -1;
    }
    __syncthreads();
    if (threadIdx.x < C)
        sbase[threadIdx.x] = atomicAdd(&cursor2[threadIdx.x * CSTR], lcur[threadIdx.x]);
    __syncthreads();
#pragma unroll
    for (int j = 0; j < SPB / 256; ++j)
        if (myt[j] >= 0)
            perm[(myt[j] << CAPLG) + sbase[myt[j]] + myr[j]] = base + j * 256 + threadIdx.x;
}

// ---------------------------------------------------------------------------
// Main pass: block = (class k, split p). Lanes 0-31 row A, 32-63 row B
// (float4 = 4 cols/lane). Depth-2 software pipeline hides L3 gather latency
// under the transcendentals. Epilogue: LDS cross-wave reduce, then TRANSPOSED
// partial store: partial[t * NMB + blockIdx] so the finalize pass reads
// coalesced columns. t: 0..127 sum_p, 128..255 sum_logneg, 256 pos.
__global__ __launch_bounds__(256)
void main_kernel(const float* __restrict__ x, const int* __restrict__ perm,
                 const int* __restrict__ cursor2, float* __restrict__ partial) {
    const int k = blockIdx.x / SPLIT;
    const int p = blockIdx.x % SPLIT;
    const int n = min(cursor2[k * CSTR], CAP);
    const int chunk = (n + SPLIT - 1) / SPLIT;
    const int s0 = min(p * chunk, n);
    const int s1 = min(s0 + chunk, n);

    const int tid  = threadIdx.x;
    const int wave = tid >> 6;
    const int lane = tid & 63;
    const int half = lane >> 5;          // 0 => row A, 1 => row B
    const int l5   = lane & 31;
    const int c0   = l5 << 2;            // this lane's first of 4 columns
    const bool poslane = (l5 == (k >> 2));
    const int  ksub = k & 3;

    const int wlen = (s1 - s0 + 3) >> 2; // per-wave contiguous sub-range
    const int ws0  = s0 + wave * wlen;
    const int ws1  = min(ws0 + wlen, s1);

    const int* bperm = perm + (k << CAPLG);

    float ap0=0,ap1=0,ap2=0,ap3=0;       // sum p
    float sx0=0,sx1=0,sx2=0,sx3=0;       // sum x
    float sl0=0,sl1=0,sl2=0,sl3=0;       // sum log2(1+exp(-x))
    float apos = 0.f;

    for (int tbase = ws0; tbase < ws1; tbase += 64) {
        const int tl = min(64, ws1 - tbase);
        const int pv = (lane < tl) ? bperm[tbase + lane] : 0;  // one load / 64 samples
        const int h  = (tl + 1) >> 1;

        // pipeline prologue: 2 row-pairs in flight
        int iA = __shfl(pv, 0);
        int iB = __shfl(pv, (h < tl) ? h : 0);
        float4 cur = *reinterpret_cast<const float4*>(x + (size_t)(half ? iB : iA) * C + c0);
        float4 nxt = cur;
        if (h > 1) {
            iA = __shfl(pv, 1);
            iB = __shfl(pv, (1 + h < tl) ? 1 + h : 1);
            nxt = *reinterpret_cast<const float4*>(x + (size_t)(half ? iB : iA) * C + c0);
        }
        for (int j = 0; j < h; ++j) {
            float4 fut = cur;
            if (j + 2 < h) {             // issue load 2 iterations ahead
                iA = __shfl(pv, j + 2);
                iB = __shfl(pv, (j + 2 + h < tl) ? j + 2 + h : j + 2);
                fut = *reinterpret_cast<const float4*>(x + (size_t)(half ? iB : iA) * C + c0);
            }
            const bool valid = (half == 0) || (j + h < tl);
            if (valid) {
                float e, u, lu0, lu1, lu2, lu3;
                e = __expf(-cur.x); u = 1.f + e; lu0 = __log2f(u);
                ap0 += fast_rcp(u); sx0 += cur.x; sl0 += lu0;
                e = __expf(-cur.y); u = 1.f + e; lu1 = __log2f(u);
                ap1 += fast_rcp(u); sx1 += cur.y; sl1 += lu1;
                e = __expf(-cur.z); u = 1.f + e; lu2 = __log2f(u);
                ap2 += fast_rcp(u); sx2 += cur.z; sl2 += lu2;
                e = __expf(-cur.w); u = 1.f + e; lu3 = __log2f(u);
                ap3 += fast_rcp(u); sx3 += cur.w; sl3 += lu3;
                if (poslane) {
                    float lsel = (ksub & 2) ? ((ksub & 1) ? lu3 : lu2)
                                            : ((ksub & 1) ? lu1 : lu0);
                    apos += lsel;
                }
            }
            cur = nxt; nxt = fut;
        }
    }

    // ---- cross-wave/half LDS reduce (plain float4 writes, no atomics) ----
    __shared__ __align__(16) float sP[8][C];
    __shared__ __align__(16) float sX[8][C];
    __shared__ __align__(16) float sL[8][C];
    __shared__ float sPos[8];
    const int g = (wave << 1) | half;
    *reinterpret_cast<float4*>(&sP[g][c0]) = make_float4(ap0, ap1, ap2, ap3);
    *reinterpret_cast<float4*>(&sX[g][c0]) = make_float4(sx0, sx1, sx2, sx3);
    *reinterpret_cast<float4*>(&sL[g][c0]) = make_float4(sl0, sl1, sl2, sl3);
    if (poslane) sPos[g] = apos;
    __syncthreads();

    const int bq = blockIdx.x;
    if (tid < C) {                        // sum_probs for column tid
        float s = 0.f;
#pragma unroll
        for (int g2 = 0; g2 < 8; ++g2) s += sP[g2][tid];
        partial[(size_t)tid * NMB + bq] = s;
    } else {                              // sum_logneg: -sum(x) - ln2*sum(log2(1+e))
        const int t = tid - C;
        float sx = 0.f, sl = 0.f;
#pragma unroll
        for (int g2 = 0; g2 < 8; ++g2) { sx += sX[g2][t]; sl += sL[g2][t]; }
        partial[(size_t)(C + t) * NMB + bq] = -sx - LN2F * sl;
    }
    if (tid == 0) {
        float s = 0.f;
#pragma unroll
        for (int g2 = 0; g2 < 8; ++g2) s += sPos[g2];
        partial[(size_t)(2 * C) * NMB + bq] = -LN2F * s;   // sum ln(p_target)
    }
}

// ---------------------------------------------------------------------------
// Fused finalize: block k reduces its two coalesced partial columns, does the
// masked softmax for column k, then a ticket picks the last block to sum all
// column partials and write the scalar output.
__global__ __launch_bounds__(256)
void finalize_kernel(const float* __restrict__ partial, const int* __restrict__ cursor2,
                     float* __restrict__ colpart, int* __restrict__ ticket,
                     float* __restrict__ out) {
    const int k   = blockIdx.x;
    const int tid = threadIdx.x;

    __shared__ float spcol[C], slcol[C];
    __shared__ float sposr[16];

    // phase 1: reduce 2048 partials -> per-row sums. thread t: row j=t>>1,
    // eight consecutive split-entries (coalesced float4 pairs).
    {
        const int j    = tid >> 1;
        const int base = j * SPLIT + (tid & 1) * 8;
        const float4* rp = reinterpret_cast<const float4*>(partial + (size_t)k * NMB + base);
        const float4* rl = reinterpret_cast<const float4*>(partial + (size_t)(C + k) * NMB + base);
        float4 a = rp[0], b = rp[1];
        float accP = a.x + a.y + a.z + a.w + b.x + b.y + b.z + b.w;
        a = rl[0]; b = rl[1];
        float accL = a.x + a.y + a.z + a.w + b.x + b.y + b.z + b.w;
        accP += __shfl_xor(accP, 1);
        accL += __shfl_xor(accL, 1);
        if ((tid & 1) == 0) { spcol[j] = accP; slcol[j] = accL; }
        if (tid < SPLIT) sposr[tid] = partial[(size_t)(2 * C) * NMB + k * SPLIT + tid];
    }
    __syncthreads();

    // phase 2: wave 0 does the masked column softmax (lane l: rows l, l+64)
    if (tid < 64) {
        const int l = tid, j0 = l, j1 = l + 64;
        const float c0 = (float)cursor2[j0 * CSTR];
        const float c1 = (float)cursor2[j1 * CSTR];
        const bool  v0 = (j0 != k) && (c0 > 0.f);
        const bool  v1 = (j1 != k) && (c1 > 0.f);
        const float x0 = v0 ? spcol[j0] / c0 : -INFINITY;
        const float x1 = v1 ? spcol[j1] / c1 : -INFINITY;

        float m = fmaxf(x0, x1);
#pragma unroll
        for (int d = 1; d < 64; d <<= 1) m = fmaxf(m, __shfl_xor(m, d));

        float w0 = v0 ? __expf(x0 - m) : 0.f;
        float w1 = v1 ? __expf(x1 - m) : 0.f;
        float den = w0 + w1;
        float num = (v0 ? w0 * (slcol[j0] / c0) : 0.f)
                  + (v1 ? w1 * (slcol[j1] / c1) : 0.f);
#pragma unroll
        for (int d = 1; d < 64; d <<= 1) { den += __shfl_xor(den, d); num += __shfl_xor(num, d); }

        int last = 0;
        if (l == 0) {
            float colneg = (den > 0.f) ? num / den : 0.f;
            float ck     = (float)cursor2[k * CSTR];
            float ps     = 0.f;
#pragma unroll
            for (int q = 0; q < SPLIT; ++q) ps += sposr[q];
            float pk = (ck > 0.f) ? ps / ck : 0.f;
            colpart[k] = colneg + pk;
            __threadfence();                       // publish colpart before ticket
            last = (atomicAdd(ticket, 1) == C - 1);
        }
        last = __shfl(last, 0);
        if (last) {                                 // last block: global sum -> out
            __threadfence();                        // acquire others' colpart
            float s = colpart[l] + colpart[l + 64];
#pragma unroll
            for (int d = 1; d < 64; d <<= 1) s += __shfl_xor(s, d);
            if (l == 0) out[0] = -s;
        }
    }
}

// ---------------------------------------------------------------------------
extern "C" void kernel_launch(void* const* d_in, const int* in_sizes, int n_in,
                              void* d_out, int out_size, void* d_ws, size_t ws_size,
                              hipStream_t stream) {
    const float* x   = (const float*)d_in[0];
    const int*   tgt = (const int*)d_in[1];
    const int B = in_sizes[1];

    int*   cursor2 = (int*)d_ws;                          // C*CSTR ints (+1 line ticket)
    int*   ticket  = cursor2 + C * CSTR;                  // 1 int (own line)
    int*   perm    = cursor2 + C * CSTR + CSTR;           // C*CAP ints
    float* partial = (float*)(perm + C * CAP);            // (2C+1)*NMB floats
    float* colpart = partial + (size_t)(2 * C + 1) * NMB; // C floats

    hipMemsetAsync(cursor2, 0, (C * CSTR + CSTR) * sizeof(int), stream);
    scatter_kernel<<<(B + SPB - 1) / SPB, 256, 0, stream>>>(tgt, cursor2, perm, B);
    main_kernel<<<NMB, 256, 0, stream>>>(x, perm, cursor2, partial);
    finalize_kernel<<<C, 256, 0, stream>>>(partial, cursor2, colpart, ticket, (float*)d_out);
}